// Round 14
// baseline (108.638 us; speedup 1.0000x reference)
//
#include <hip/hip_runtime.h>

// PrimalDualNetwork: 10-iter Chambolle-Pock ROF on 2048x2048 fp32.
// R21 = R20 + co-resident-block de-phase-lock. R20 post-mortem: at
// full residency VALUBusy pins at ~63% -- 37% of cycles ALL 8
// waves/SIMD are parked at the same waitcnt+barrier. The two blocks
// per CU start in the same round, run identical code -> barriers
// phase-align; neither fills the other's drain (~17us residual).
// LDS-op audit: 9 ops/unit-iter is near-minimal (merges break
// contiguous-stride bank behavior or the 155KB 2-block LDS budget).
// Changes:
//  (a) per-CU ticket (ws atomic, CU id from s_getreg HW_ID[15:8]):
//      2nd block on each CU sleeps ~1400cyc (~half a phase) before
//      the iteration loop -> pair runs anti-phase. Round 2 re-staggers
//      (tickets 2,3). No barrier interaction (sleep is pre-loop).
//  (b) final redundant __syncthreads deleted (t=9 peeled).
// Tripwire: dur flat & VALUBusy ~63 => stall is intra-block dep
// latency, structure at ceiling. absmax exactly 0.00390625.

namespace {
constexpr int M = 2048, N = 2048;
constexpr float SIGMA     = 1.0f / (7.0f * 0.01f);
constexpr float TAUIS     = 0.01f * (7.0f * 0.01f);  // tau/sigma
constexpr float LT        = 4.0f * 0.01f;
constexpr float INV_DEN   = 1.0f / (1.0f + 4.0f * 0.01f);
constexpr float TAUIS_ID  = TAUIS * INV_DEN;
constexpr float LT_ID     = LT * INV_DEN;
constexpr int TW = 64, TH = 64;     // output tile
constexpr int PC = 88;              // plane cols (12 + 64 + 12)
constexpr int PR = 84;              // plane rows (10 + 64 + 10)
constexpr int UPR = 22;             // h4 units per row == PC/4
constexpr int PROC = 83;            // rows 0..82 processed (83 read-only)
constexpr int NU = PROC * UPR;      // 1826
constexpr int NT = 1024;            // 16 waves
constexpr int NPASS = 2;            // 2*1024 >= NU (and >= PR*UPR=1848)
constexpr int GY = M / TH;          // 32  (exact: no partial tiles)
} // namespace

typedef _Float16 h4 __attribute__((ext_vector_type(4)));
typedef float    f2 __attribute__((ext_vector_type(2)));
typedef unsigned uint32;

#define HWREG(id, off, sz) ((id) | ((off) << 6) | (((sz) - 1) << 11))

__device__ inline h4 h4splat(float v) {
    _Float16 s = (_Float16)v;
    return (h4){s, s, s, s};
}
__device__ inline int imax(int a, int b) { return a > b ? a : b; }
__device__ inline uint32 abit(uint32 hi, uint32 lo) {
    return __builtin_amdgcn_alignbit(hi, lo, 16);
}
__device__ inline h4 clamp1(h4 v) {
    return __builtin_elementwise_min(
               __builtin_elementwise_max(v, h4splat(-1.f)), h4splat(1.f));
}
// packed f32->f16 (RTZ); builtin returns __fp16x2 -> pass through uint32
__device__ inline uint32 pkrtz(float a, float b) {
    return __builtin_bit_cast(uint32, __builtin_amdgcn_cvt_pkrtz(a, b));
}

__global__ __launch_bounds__(NT, 8) void pd_fused(
    const float* __restrict__ img, float* __restrict__ out,
    const float* __restrict__ w1p, const float* __restrict__ w2p,
    int* __restrict__ ws)
{
    __shared__ __align__(16) _Float16 sXT16[PR * PC];   // 14784 B (xt, fp16)
    __shared__ __align__(16) _Float16 sQV[PR * PC];     // 14784 B
    __shared__ __align__(16) _Float16 sCI[PR * PC];     // 14784 B (LT_ID*img)
    __shared__ __align__(16) _Float16 sSW[2 * PR * PC]; // 29568 B (swh|swv)
    __shared__ __align__(16) _Float16 sQH3[1840];       //  3680 B (qH[3]/unit)
    __shared__ int sStag;

    const int tid  = threadIdx.x;
    const int c0 = blockIdx.x * TW, r0 = blockIdx.y * TH;
    const int gr0 = r0 - 10, gc0 = c0 - 12;
    const float w1 = w1p[0], w2 = w2p[0];

    // per-CU arrival ticket: 2nd block on this CU will stagger
    if (tid == 0) {
        int st = 0;
        if (ws) {
            uint32 cu = __builtin_amdgcn_s_getreg(HWREG(4, 8, 8)); // HW_ID[15:8]
            st = atomicAdd(&ws[cu & 255], 1) & 1;
        }
        sStag = st;
    }

    // cone deactivation threshold per pass (active iff rem >= d)
    int dth_[NPASS];
    #pragma unroll
    for (int p = 0; p < NPASS; ++p) {
        int u = tid + p * NT;
        int li = u / UPR, lc = (u - li * UPR) * 4;
        int d = imax(imax(9 - li, li - (TH + 9)), imax(8 - lc, lc - 75));
        d = imax(d, 0);
        if (u >= NU) d = 100;
        dth_[p] = d;
    }

    // ---- stage img -> sXT16 (fp16; 0 outside image) ----
    #pragma unroll
    for (int p = 0; p < NPASS; ++p) {
        int su = tid + p * NT;
        if (su < PR * UPR) {
            int li = su / UPR, uj = su - li * UPR;
            int gi = gr0 + li, gj = gc0 + uj * 4;
            float4 v = make_float4(0.f, 0.f, 0.f, 0.f);
            if ((unsigned)gi < (unsigned)M && (unsigned)gj <= (unsigned)(N - 4))
                v = *(const float4*)&img[(size_t)gi * N + gj];
            h4 h; h[0] = (_Float16)v.x; h[1] = (_Float16)v.y;
                  h[2] = (_Float16)v.z; h[3] = (_Float16)v.w;
            *(h4*)&sXT16[su * 4] = h;
        }
    }
    __syncthreads();

    // register state (28 named at 32 cap): x fp32 pairs, xt/y/q/qv fp16
    f2 xr2[NPASS][2];
    h4 xt16[NPASS], yh[NPASS], yv[NPASS], qH[NPASS], qvr[NPASS];

    // ---- init (== dual(0)): sigma*w -> sSW, ci -> sCI, y0, q0 ----
    #pragma unroll
    for (int p = 0; p < NPASS; ++p) {
        int u = tid + p * NT;
        if (u < NU) {
            int bF = u * 4;
            int li = u / UPR;
            int gi = gr0 + li, gjb = gc0 + (u - li * UPR) * 4;
            h4 c16 = *(const h4*)&sXT16[bF];
            uint32 rrp = *(const uint32*)&sXT16[bF + 4];
            h4 dn = *(const h4*)&sXT16[bF + PC];
            uint2 xu = __builtin_bit_cast(uint2, c16);
            h4 xsh = __builtin_bit_cast(h4,
                         make_uint2(abit(xu.y, xu.x), abit(rrp, xu.y)));
            bool rok = (unsigned)gi < (unsigned)M;
            bool vok = rok && (gi < M - 1);
            h4 qv, swhv, swvv, civ;
            #pragma unroll
            for (int l = 0; l < 4; ++l) {
                int gj = gjb + l;
                bool cok = (unsigned)gj < (unsigned)N;
                bool hok = rok && cok && (gj < N - 1);
                bool vk  = vok && cok;
                float xf  = (float)c16[l];
                float ghf = hok ? (float)xsh[l] - xf : 0.f;
                float gvf = vk  ? (float)dn[l]  - xf : 0.f;
                float wh = fmaf(w2, __expf(-fabsf(ghf)), w1);
                float wv = fmaf(w2, __expf(-fabsf(gvf)), w1);
                float y0h = fminf(fmaxf(ghf * fmaf(SIGMA, wh, 1.f), -1.f), 1.f);
                float y0v = fminf(fmaxf(gvf * fmaf(SIGMA, wv, 1.f), -1.f), 1.f);
                float sh = hok ? SIGMA * wh : 0.f;
                float sv = vk  ? SIGMA * wv : 0.f;
                yh[p][l]   = (_Float16)y0h;  yv[p][l] = (_Float16)y0v;
                swhv[l]    = (_Float16)sh;   swvv[l]  = (_Float16)sv;
                qH[p][l]   = (_Float16)(sh * y0h);
                qv[l]      = (_Float16)(sv * y0v);
                civ[l]     = (_Float16)(LT_ID * xf);
                xr2[p][l >> 1][l & 1] = xf;
            }
            xt16[p] = c16;
            qvr[p]  = qv;
            *(h4*)&sSW[bF * 2]     = swhv;   // unit u: halves [8u, 8u+4)
            *(h4*)&sSW[bF * 2 + 4] = swvv;   //          halves [8u+4, 8u+8)
            *(h4*)&sCI[bF]  = civ;
            *(h4*)&sQV[bF]  = qv;
            sQH3[u] = qH[p][3];
        }
    }
    __syncthreads();

    // anti-phase stagger: 2nd block on this CU sleeps ~half a phase
    if (sStag) {
        __builtin_amdgcn_s_sleep(11);   // ~704 cyc
        __builtin_amdgcn_s_sleep(11);   // ~1408 total
    }

    // ---- dual(t>=1): y = clamp(y + sw*grad16(xt)); q = sw*y
    //      sw via ONE b128 read of the interleaved plane ----
    auto dual = [&](int rem) {
        #pragma unroll
        for (int p = 0; p < NPASS; ++p) {
            if (rem >= dth_[p]) {
                int bF = (tid + p * NT) * 4;
                uint32 rrp = *(const uint32*)&sXT16[bF + 4];
                h4 dn  = *(const h4*)&sXT16[bF + PC];
                uint4 swp = *(const uint4*)&sSW[bF * 2];     // b128
                h4 swh = __builtin_bit_cast(h4, make_uint2(swp.x, swp.y));
                h4 swv = __builtin_bit_cast(h4, make_uint2(swp.z, swp.w));
                uint2 xu = __builtin_bit_cast(uint2, xt16[p]);
                h4 xsh = __builtin_bit_cast(h4,
                             make_uint2(abit(xu.y, xu.x), abit(rrp, xu.y)));
                h4 ghh = xsh - xt16[p];              // v_pk_sub_f16
                h4 gvh = dn  - xt16[p];
                h4 nh = clamp1(yh[p] + swh * ghh);   // sw=0 masks borders
                h4 nv = clamp1(yv[p] + swv * gvh);
                yh[p] = nh; yv[p] = nv;
                h4 qh = swh * nh;                    // q = sigma*w*y
                h4 qv = swv * nv;
                qH[p] = qh; qvr[p] = qv;
                *(h4*)&sQV[bF] = qv;
                sQH3[bF >> 2] = qh[3];
            }
        }
    };

    // ---- primal: s16 = TAUIS_ID*dvg + ci (packed f16);
    //      xn = fma(INV_DEN, xo, cvt(s16)); xt = 1.5xn - 0.5xo;
    //      own qv from register (qvr); repack via v_cvt_pkrtz.
    //      last: fp32 store, skip LDS. ----
    const f2 kID  = {INV_DEN,  INV_DEN};
    const f2 k15  = {1.5f, 1.5f};
    const f2 km05 = {-0.5f, -0.5f};
    const h4 kTS16 = h4splat(TAUIS_ID);
    auto primal = [&](int rem, bool last) {
        #pragma unroll
        for (int p = 0; p < NPASS; ++p) {
            if (rem >= dth_[p]) {
                int u = tid + p * NT, bF = u * 4;
                int bu = (bF >= UPR * 4) ? bF - PC : bF;  // row-0 junk tolerated
                h4 qvu = *(const h4*)&sQV[bu];
                h4 civ = *(const h4*)&sCI[bF];
                uint32 qhl = *(const unsigned short*)&sQH3[imax(u - 1, 0)];
                uint2 qu = __builtin_bit_cast(uint2, qH[p]);
                h4 qsh = __builtin_bit_cast(h4,
                             make_uint2(abit(qu.x, qhl << 16), abit(qu.y, qu.x)));
                h4 dvg = (qH[p] - qsh) + (qvr[p] - qvu);  // v_pk_sub/add_f16
                h4 s16 = kTS16 * dvg + civ;               // packed f16 fma
                f2 s0 = {(float)s16[0], (float)s16[1]};
                f2 s1 = {(float)s16[2], (float)s16[3]};
                f2 xo0 = xr2[p][0], xo1 = xr2[p][1];
                f2 xn0 = __builtin_elementwise_fma(kID, xo0, s0);
                f2 xn1 = __builtin_elementwise_fma(kID, xo1, s1);
                xr2[p][0] = xn0; xr2[p][1] = xn1;
                f2 xt0 = __builtin_elementwise_fma(k15, xn0, xo0 * km05);
                f2 xt1 = __builtin_elementwise_fma(k15, xn1, xo1 * km05);
                if (!last) {
                    h4 nx = __builtin_bit_cast(h4,
                        make_uint2(pkrtz(xt0[0], xt0[1]),
                                   pkrtz(xt1[0], xt1[1])));
                    xt16[p] = nx;
                    *(h4*)&sXT16[bF] = nx;
                } else {
                    int li = u / UPR, uj = u - li * UPR;
                    int gi = gr0 + li;
                    if (li >= 10 && uj >= 3 && uj <= 18 && gi < M) {
                        *(float4*)&out[(size_t)gi * N + (gc0 + uj * 4)] =
                            make_float4(xt0[0], xt0[1], xt1[0], xt1[1]);
                    }
                }
            }
        }
    };

    primal(9, false);          // t=0 (dual(0) fused into init)
    __syncthreads();
    #pragma unroll 1
    for (int t = 1; t < 9; ++t) {
        int rem = 9 - t;
        dual(rem);
        __syncthreads();
        primal(rem, false);
        __syncthreads();
    }
    dual(0);
    __syncthreads();
    primal(0, true);           // final: global store, no trailing barrier
}

extern "C" void kernel_launch(void* const* d_in, const int* in_sizes, int n_in,
                              void* d_out, int out_size, void* d_ws, size_t ws_size,
                              hipStream_t stream)
{
    const float* img = (const float*)d_in[0];
    const float* w1  = (const float*)d_in[1];
    const float* w2  = (const float*)d_in[2];
    float* out = (float*)d_out;

    int* ws = nullptr;
    if (d_ws && ws_size >= 1024) {
        ws = (int*)d_ws;
        hipMemsetAsync(d_ws, 0, 1024, stream);   // per-CU ticket counters
    }

    dim3 grid(N / TW, GY);   // 32 x 32 = 1024 blocks = 2/CU x 2 rounds
    pd_fused<<<grid, NT, 0, stream>>>(img, out, w1, w2, ws);
}

// Round 15
// 107.519 us; speedup vs baseline: 1.0104x; 1.0104x over previous
//
#include <hip/hip_runtime.h>

// PrimalDualNetwork: 10-iter Chambolle-Pock ROF on 2048x2048 fp32.
// R22 = R20 (stagger reverted -- R21 null) + z-substitution:
//   x' = ID*x + TS_ID*dv + LT_ID*img  with  z = x - img  gives
//   z' = ID*z + TS_ID*dv  EXACTLY (ID - 1 + LT_ID == 0), z0 = 0.
//   wt = 1.5z' - 0.5z = xt - img is stored in the xt plane; dual
//   reconstructs grad(xt) = grad(wt) + grad(img), with grad(img)
//   (gih/giv, fp16, masked) held in REGISTERS (init-computed consts).
// Cuts per unit-iter: primal loses the sCI read (LDS 10 -> 9) and its
// f32 tail (s16-fma + 4 cvts + 4 f2fma + 2 pkrtz -> ~8 pk-f16 ops,
// -6 VALU); dual +2 pk_add. sCI plane now holds img fp16 for the one
// final-store read. Regs +4 named (28 -> 32, R20-scale, mild spill ok).
// Numerics: z fp16 recurrence ~1.2e-3 + grad recomposition ~1e-3 +
// img16 2.4e-4 -> absmax ~0.005-0.009 (budget 0.0177).
// Tripwires: absmax > 0.015 => z back to fp32; WRITE > 50 MB => spill;
// dur flat => 2-barrier structure ceiling, declare next round.

namespace {
constexpr int M = 2048, N = 2048;
constexpr float SIGMA     = 1.0f / (7.0f * 0.01f);
constexpr float TAUIS     = 0.01f * (7.0f * 0.01f);  // tau/sigma
constexpr float LT        = 4.0f * 0.01f;
constexpr float INV_DEN   = 1.0f / (1.0f + 4.0f * 0.01f);
constexpr float TAUIS_ID  = TAUIS * INV_DEN;
constexpr int TW = 64, TH = 64;     // output tile
constexpr int PC = 88;              // plane cols (12 + 64 + 12)
constexpr int PR = 84;              // plane rows (10 + 64 + 10)
constexpr int UPR = 22;             // h4 units per row == PC/4
constexpr int PROC = 83;            // rows 0..82 processed (83 read-only)
constexpr int NU = PROC * UPR;      // 1826
constexpr int NT = 1024;            // 16 waves
constexpr int NPASS = 2;            // 2*1024 >= NU (and >= PR*UPR=1848)
constexpr int GY = M / TH;          // 32  (exact: no partial tiles)
} // namespace

typedef _Float16 h4 __attribute__((ext_vector_type(4)));
typedef float    f2 __attribute__((ext_vector_type(2)));
typedef unsigned uint32;

__device__ inline h4 h4splat(float v) {
    _Float16 s = (_Float16)v;
    return (h4){s, s, s, s};
}
__device__ inline int imax(int a, int b) { return a > b ? a : b; }
__device__ inline uint32 abit(uint32 hi, uint32 lo) {
    return __builtin_amdgcn_alignbit(hi, lo, 16);
}
__device__ inline h4 clamp1(h4 v) {
    return __builtin_elementwise_min(
               __builtin_elementwise_max(v, h4splat(-1.f)), h4splat(1.f));
}

__global__ __launch_bounds__(NT, 8) void pd_fused(
    const float* __restrict__ img, float* __restrict__ out,
    const float* __restrict__ w1p, const float* __restrict__ w2p)
{
    __shared__ __align__(16) _Float16 sXT16[PR * PC];   // 14784 B (wt plane)
    __shared__ __align__(16) _Float16 sQV[PR * PC];     // 14784 B
    __shared__ __align__(16) _Float16 sIM[PR * PC];     // 14784 B (img fp16)
    __shared__ __align__(16) _Float16 sSW[2 * PR * PC]; // 29568 B (swh|swv)
    __shared__ __align__(16) _Float16 sQH3[1840];       //  3680 B (qH[3]/unit)

    const int tid  = threadIdx.x;
    const int c0 = blockIdx.x * TW, r0 = blockIdx.y * TH;
    const int gr0 = r0 - 10, gc0 = c0 - 12;
    const float w1 = w1p[0], w2 = w2p[0];

    // cone deactivation threshold per pass (active iff rem >= d)
    int dth_[NPASS];
    #pragma unroll
    for (int p = 0; p < NPASS; ++p) {
        int u = tid + p * NT;
        int li = u / UPR, lc = (u - li * UPR) * 4;
        int d = imax(imax(9 - li, li - (TH + 9)), imax(8 - lc, lc - 75));
        d = imax(d, 0);
        if (u >= NU) d = 100;
        dth_[p] = d;
    }

    // ---- stage img -> sXT16 (fp16; 0 outside image) ----
    #pragma unroll
    for (int p = 0; p < NPASS; ++p) {
        int su = tid + p * NT;
        if (su < PR * UPR) {
            int li = su / UPR, uj = su - li * UPR;
            int gi = gr0 + li, gj = gc0 + uj * 4;
            float4 v = make_float4(0.f, 0.f, 0.f, 0.f);
            if ((unsigned)gi < (unsigned)M && (unsigned)gj <= (unsigned)(N - 4))
                v = *(const float4*)&img[(size_t)gi * N + gj];
            h4 h; h[0] = (_Float16)v.x; h[1] = (_Float16)v.y;
                  h[2] = (_Float16)v.z; h[3] = (_Float16)v.w;
            *(h4*)&sXT16[su * 4] = h;
        }
    }
    __syncthreads();

    // register state (32 named at 32 cap): z/wt/y/q/qv/gi packed fp16
    h4 zr[NPASS], wt16[NPASS], yh[NPASS], yv[NPASS],
       qH[NPASS], qvr[NPASS], gih[NPASS], giv[NPASS];

    // ---- init (== dual(0)): sw -> sSW, img -> sIM, gi -> regs, y0, q0 ----
    #pragma unroll
    for (int p = 0; p < NPASS; ++p) {
        int u = tid + p * NT;
        if (u < NU) {
            int bF = u * 4;
            int li = u / UPR;
            int gi = gr0 + li, gjb = gc0 + (u - li * UPR) * 4;
            h4 c16 = *(const h4*)&sXT16[bF];
            uint32 rrp = *(const uint32*)&sXT16[bF + 4];
            h4 dn = *(const h4*)&sXT16[bF + PC];
            uint2 xu = __builtin_bit_cast(uint2, c16);
            h4 xsh = __builtin_bit_cast(h4,
                         make_uint2(abit(xu.y, xu.x), abit(rrp, xu.y)));
            bool rok = (unsigned)gi < (unsigned)M;
            bool vok = rok && (gi < M - 1);
            h4 qv, swhv, swvv, gh16, gv16;
            #pragma unroll
            for (int l = 0; l < 4; ++l) {
                int gj = gjb + l;
                bool cok = (unsigned)gj < (unsigned)N;
                bool hok = rok && cok && (gj < N - 1);
                bool vk  = vok && cok;
                float xf  = (float)c16[l];
                float ghf = hok ? (float)xsh[l] - xf : 0.f;
                float gvf = vk  ? (float)dn[l]  - xf : 0.f;
                float wh = fmaf(w2, __expf(-fabsf(ghf)), w1);
                float wv = fmaf(w2, __expf(-fabsf(gvf)), w1);
                float y0h = fminf(fmaxf(ghf * fmaf(SIGMA, wh, 1.f), -1.f), 1.f);
                float y0v = fminf(fmaxf(gvf * fmaf(SIGMA, wv, 1.f), -1.f), 1.f);
                float sh = hok ? SIGMA * wh : 0.f;
                float sv = vk  ? SIGMA * wv : 0.f;
                yh[p][l]   = (_Float16)y0h;  yv[p][l] = (_Float16)y0v;
                swhv[l]    = (_Float16)sh;   swvv[l]  = (_Float16)sv;
                qH[p][l]   = (_Float16)(sh * y0h);
                qv[l]      = (_Float16)(sv * y0v);
                gh16[l]    = (_Float16)ghf;  gv16[l]  = (_Float16)gvf;
            }
            gih[p] = gh16; giv[p] = gv16;
            zr[p]  = h4splat(0.f);
            qvr[p] = qv;
            *(h4*)&sSW[bF * 2]     = swhv;   // unit u: halves [8u, 8u+4)
            *(h4*)&sSW[bF * 2 + 4] = swvv;   //          halves [8u+4, 8u+8)
            *(h4*)&sIM[bF]  = c16;           // img fp16 (final store only)
            *(h4*)&sQV[bF]  = qv;
            sQH3[u] = qH[p][3];
        }
    }
    __syncthreads();

    // ---- dual(t>=1): grad(xt) = grad(wt) + grad(img);
    //      y = clamp(y + sw*g); q = sw*y ----
    auto dual = [&](int rem) {
        #pragma unroll
        for (int p = 0; p < NPASS; ++p) {
            if (rem >= dth_[p]) {
                int bF = (tid + p * NT) * 4;
                uint32 rrp = *(const uint32*)&sXT16[bF + 4];
                h4 dn  = *(const h4*)&sXT16[bF + PC];
                uint4 swp = *(const uint4*)&sSW[bF * 2];     // b128
                h4 swh = __builtin_bit_cast(h4, make_uint2(swp.x, swp.y));
                h4 swv = __builtin_bit_cast(h4, make_uint2(swp.z, swp.w));
                uint2 xu = __builtin_bit_cast(uint2, wt16[p]);
                h4 wsh = __builtin_bit_cast(h4,
                             make_uint2(abit(xu.y, xu.x), abit(rrp, xu.y)));
                h4 ghh = (wsh - wt16[p]) + gih[p];    // pk_sub + pk_add
                h4 gvh = (dn  - wt16[p]) + giv[p];
                h4 nh = clamp1(yh[p] + swh * ghh);    // sw=0 masks borders
                h4 nv = clamp1(yv[p] + swv * gvh);
                yh[p] = nh; yv[p] = nv;
                h4 qh = swh * nh;                     // q = sigma*w*y
                h4 qv = swv * nv;
                qH[p] = qh; qvr[p] = qv;
                *(h4*)&sQV[bF] = qv;
                sQH3[bF >> 2] = qh[3];
            }
        }
    };

    // ---- primal (z-space, all packed fp16):
    //      z' = ID*z + TS_ID*dvg; wt = 1.5z' - 0.5z.
    //      last: out = wt + img (fp32 store). ----
    const h4 kIDh  = h4splat(INV_DEN);
    const h4 kTSh  = h4splat(TAUIS_ID);
    const h4 k15h  = h4splat(1.5f);
    const h4 km05h = h4splat(-0.5f);
    auto primal = [&](int rem, bool last) {
        #pragma unroll
        for (int p = 0; p < NPASS; ++p) {
            if (rem >= dth_[p]) {
                int u = tid + p * NT, bF = u * 4;
                int bu = (bF >= UPR * 4) ? bF - PC : bF;  // row-0 junk tolerated
                h4 qvu = *(const h4*)&sQV[bu];
                uint32 qhl = *(const unsigned short*)&sQH3[imax(u - 1, 0)];
                uint2 qu = __builtin_bit_cast(uint2, qH[p]);
                h4 qsh = __builtin_bit_cast(h4,
                             make_uint2(abit(qu.x, qhl << 16), abit(qu.y, qu.x)));
                h4 dvg = (qH[p] - qsh) + (qvr[p] - qvu);  // v_pk_sub/add_f16
                h4 zo = zr[p];
                h4 zn = kIDh * zo + kTSh * dvg;           // pk_mul + pk_fma
                zr[p] = zn;
                h4 wt = k15h * zn + km05h * zo;
                if (!last) {
                    wt16[p] = wt;
                    *(h4*)&sXT16[bF] = wt;
                } else {
                    int li = u / UPR, uj = u - li * UPR;
                    int gi = gr0 + li;
                    if (li >= 10 && uj >= 3 && uj <= 18 && gi < M) {
                        h4 im = *(const h4*)&sIM[bF];
                        *(float4*)&out[(size_t)gi * N + (gc0 + uj * 4)] =
                            make_float4((float)wt[0] + (float)im[0],
                                        (float)wt[1] + (float)im[1],
                                        (float)wt[2] + (float)im[2],
                                        (float)wt[3] + (float)im[3]);
                    }
                }
            }
        }
    };

    primal(9, false);          // t=0 (dual(0) fused into init)
    __syncthreads();
    #pragma unroll 1
    for (int t = 1; t < 9; ++t) {
        int rem = 9 - t;
        dual(rem);
        __syncthreads();
        primal(rem, false);
        __syncthreads();
    }
    dual(0);
    __syncthreads();
    primal(0, true);           // final: global store, no trailing barrier
}

extern "C" void kernel_launch(void* const* d_in, const int* in_sizes, int n_in,
                              void* d_out, int out_size, void* d_ws, size_t ws_size,
                              hipStream_t stream)
{
    const float* img = (const float*)d_in[0];
    const float* w1  = (const float*)d_in[1];
    const float* w2  = (const float*)d_in[2];
    float* out = (float*)d_out;

    dim3 grid(N / TW, GY);   // 32 x 32 = 1024 blocks = 2/CU x 2 rounds
    pd_fused<<<grid, NT, 0, stream>>>(img, out, w1, w2);
}

// Round 16
// 105.802 us; speedup vs baseline: 1.0268x; 1.0162x over previous
//
#include <hip/hip_runtime.h>

// PrimalDualNetwork: 10-iter Chambolle-Pock ROF on 2048x2048 fp32.
// R23 = R20 (best-measured variant: 45.5us dispatch, WRITE 28.8MB,
// absmax 0.00390625) + final-barrier peel (from R21/R22, the only
// net-positive piece of those rounds). z-substitution REVERTED: R22
// showed its VALU savings were repaid as spill traffic (WRITE 28.8 ->
// 46.6MB, FETCH +6.5MB) at the hard 32-VGPR cap.
// Session ledger (R9-R22): the {arg=8 residency, 32-VGPR codegen,
// 9-LDS-op/unit-iter, 2-barrier/iter} fixed point is closed --
// grow state => spill (R17/R18/R22); relax cap => lose residency
// (R13/R14); shrink LDS further => breaks stride/budget (audit);
// de-phase-lock => null (R21); issue diets => ~1us total (R16-R20).
// This round consolidates the best point; if flat, ceiling declared.

namespace {
constexpr int M = 2048, N = 2048;
constexpr float SIGMA     = 1.0f / (7.0f * 0.01f);
constexpr float TAUIS     = 0.01f * (7.0f * 0.01f);  // tau/sigma
constexpr float LT        = 4.0f * 0.01f;
constexpr float INV_DEN   = 1.0f / (1.0f + 4.0f * 0.01f);
constexpr float TAUIS_ID  = TAUIS * INV_DEN;
constexpr float LT_ID     = LT * INV_DEN;
constexpr int TW = 64, TH = 64;     // output tile
constexpr int PC = 88;              // plane cols (12 + 64 + 12)
constexpr int PR = 84;              // plane rows (10 + 64 + 10)
constexpr int UPR = 22;             // h4 units per row == PC/4
constexpr int PROC = 83;            // rows 0..82 processed (83 read-only)
constexpr int NU = PROC * UPR;      // 1826
constexpr int NT = 1024;            // 16 waves
constexpr int NPASS = 2;            // 2*1024 >= NU (and >= PR*UPR=1848)
constexpr int GY = M / TH;          // 32  (exact: no partial tiles)
} // namespace

typedef _Float16 h4 __attribute__((ext_vector_type(4)));
typedef float    f2 __attribute__((ext_vector_type(2)));
typedef unsigned uint32;

__device__ inline h4 h4splat(float v) {
    _Float16 s = (_Float16)v;
    return (h4){s, s, s, s};
}
__device__ inline int imax(int a, int b) { return a > b ? a : b; }
__device__ inline uint32 abit(uint32 hi, uint32 lo) {
    return __builtin_amdgcn_alignbit(hi, lo, 16);
}
__device__ inline h4 clamp1(h4 v) {
    return __builtin_elementwise_min(
               __builtin_elementwise_max(v, h4splat(-1.f)), h4splat(1.f));
}
// packed f32->f16 (RTZ); builtin returns __fp16x2 -> pass through uint32
__device__ inline uint32 pkrtz(float a, float b) {
    return __builtin_bit_cast(uint32, __builtin_amdgcn_cvt_pkrtz(a, b));
}

__global__ __launch_bounds__(NT, 8) void pd_fused(
    const float* __restrict__ img, float* __restrict__ out,
    const float* __restrict__ w1p, const float* __restrict__ w2p)
{
    __shared__ __align__(16) _Float16 sXT16[PR * PC];   // 14784 B (xt, fp16)
    __shared__ __align__(16) _Float16 sQV[PR * PC];     // 14784 B
    __shared__ __align__(16) _Float16 sCI[PR * PC];     // 14784 B (LT_ID*img)
    __shared__ __align__(16) _Float16 sSW[2 * PR * PC]; // 29568 B (swh|swv)
    __shared__ __align__(16) _Float16 sQH3[1840];       //  3680 B (qH[3]/unit)

    const int tid  = threadIdx.x;
    const int c0 = blockIdx.x * TW, r0 = blockIdx.y * TH;
    const int gr0 = r0 - 10, gc0 = c0 - 12;
    const float w1 = w1p[0], w2 = w2p[0];

    // cone deactivation threshold per pass (active iff rem >= d)
    int dth_[NPASS];
    #pragma unroll
    for (int p = 0; p < NPASS; ++p) {
        int u = tid + p * NT;
        int li = u / UPR, lc = (u - li * UPR) * 4;
        int d = imax(imax(9 - li, li - (TH + 9)), imax(8 - lc, lc - 75));
        d = imax(d, 0);
        if (u >= NU) d = 100;
        dth_[p] = d;
    }

    // ---- stage img -> sXT16 (fp16; 0 outside image) ----
    #pragma unroll
    for (int p = 0; p < NPASS; ++p) {
        int su = tid + p * NT;
        if (su < PR * UPR) {
            int li = su / UPR, uj = su - li * UPR;
            int gi = gr0 + li, gj = gc0 + uj * 4;
            float4 v = make_float4(0.f, 0.f, 0.f, 0.f);
            if ((unsigned)gi < (unsigned)M && (unsigned)gj <= (unsigned)(N - 4))
                v = *(const float4*)&img[(size_t)gi * N + gj];
            h4 h; h[0] = (_Float16)v.x; h[1] = (_Float16)v.y;
                  h[2] = (_Float16)v.z; h[3] = (_Float16)v.w;
            *(h4*)&sXT16[su * 4] = h;
        }
    }
    __syncthreads();

    // register state (28 named at 32 cap): x fp32 pairs, xt/y/q/qv fp16
    f2 xr2[NPASS][2];
    h4 xt16[NPASS], yh[NPASS], yv[NPASS], qH[NPASS], qvr[NPASS];

    // ---- init (== dual(0)): sigma*w -> sSW, ci -> sCI, y0, q0 ----
    #pragma unroll
    for (int p = 0; p < NPASS; ++p) {
        int u = tid + p * NT;
        if (u < NU) {
            int bF = u * 4;
            int li = u / UPR;
            int gi = gr0 + li, gjb = gc0 + (u - li * UPR) * 4;
            h4 c16 = *(const h4*)&sXT16[bF];
            uint32 rrp = *(const uint32*)&sXT16[bF + 4];
            h4 dn = *(const h4*)&sXT16[bF + PC];
            uint2 xu = __builtin_bit_cast(uint2, c16);
            h4 xsh = __builtin_bit_cast(h4,
                         make_uint2(abit(xu.y, xu.x), abit(rrp, xu.y)));
            bool rok = (unsigned)gi < (unsigned)M;
            bool vok = rok && (gi < M - 1);
            h4 qv, swhv, swvv, civ;
            #pragma unroll
            for (int l = 0; l < 4; ++l) {
                int gj = gjb + l;
                bool cok = (unsigned)gj < (unsigned)N;
                bool hok = rok && cok && (gj < N - 1);
                bool vk  = vok && cok;
                float xf  = (float)c16[l];
                float ghf = hok ? (float)xsh[l] - xf : 0.f;
                float gvf = vk  ? (float)dn[l]  - xf : 0.f;
                float wh = fmaf(w2, __expf(-fabsf(ghf)), w1);
                float wv = fmaf(w2, __expf(-fabsf(gvf)), w1);
                float y0h = fminf(fmaxf(ghf * fmaf(SIGMA, wh, 1.f), -1.f), 1.f);
                float y0v = fminf(fmaxf(gvf * fmaf(SIGMA, wv, 1.f), -1.f), 1.f);
                float sh = hok ? SIGMA * wh : 0.f;
                float sv = vk  ? SIGMA * wv : 0.f;
                yh[p][l]   = (_Float16)y0h;  yv[p][l] = (_Float16)y0v;
                swhv[l]    = (_Float16)sh;   swvv[l]  = (_Float16)sv;
                qH[p][l]   = (_Float16)(sh * y0h);
                qv[l]      = (_Float16)(sv * y0v);
                civ[l]     = (_Float16)(LT_ID * xf);
                xr2[p][l >> 1][l & 1] = xf;
            }
            xt16[p] = c16;
            qvr[p]  = qv;
            *(h4*)&sSW[bF * 2]     = swhv;   // unit u: halves [8u, 8u+4)
            *(h4*)&sSW[bF * 2 + 4] = swvv;   //          halves [8u+4, 8u+8)
            *(h4*)&sCI[bF]  = civ;
            *(h4*)&sQV[bF]  = qv;
            sQH3[u] = qH[p][3];
        }
    }
    __syncthreads();

    // ---- dual(t>=1): y = clamp(y + sw*grad16(xt)); q = sw*y
    //      sw via ONE b128 read of the interleaved plane ----
    auto dual = [&](int rem) {
        #pragma unroll
        for (int p = 0; p < NPASS; ++p) {
            if (rem >= dth_[p]) {
                int bF = (tid + p * NT) * 4;
                uint32 rrp = *(const uint32*)&sXT16[bF + 4];
                h4 dn  = *(const h4*)&sXT16[bF + PC];
                uint4 swp = *(const uint4*)&sSW[bF * 2];     // b128
                h4 swh = __builtin_bit_cast(h4, make_uint2(swp.x, swp.y));
                h4 swv = __builtin_bit_cast(h4, make_uint2(swp.z, swp.w));
                uint2 xu = __builtin_bit_cast(uint2, xt16[p]);
                h4 xsh = __builtin_bit_cast(h4,
                             make_uint2(abit(xu.y, xu.x), abit(rrp, xu.y)));
                h4 ghh = xsh - xt16[p];              // v_pk_sub_f16
                h4 gvh = dn  - xt16[p];
                h4 nh = clamp1(yh[p] + swh * ghh);   // sw=0 masks borders
                h4 nv = clamp1(yv[p] + swv * gvh);
                yh[p] = nh; yv[p] = nv;
                h4 qh = swh * nh;                    // q = sigma*w*y
                h4 qv = swv * nv;
                qH[p] = qh; qvr[p] = qv;
                *(h4*)&sQV[bF] = qv;
                sQH3[bF >> 2] = qh[3];
            }
        }
    };

    // ---- primal: s16 = TAUIS_ID*dvg + ci (packed f16);
    //      xn = fma(INV_DEN, xo, cvt(s16)); xt = 1.5xn - 0.5xo;
    //      own qv from register (qvr); repack via v_cvt_pkrtz.
    //      last: fp32 store, skip LDS. ----
    const f2 kID  = {INV_DEN,  INV_DEN};
    const f2 k15  = {1.5f, 1.5f};
    const f2 km05 = {-0.5f, -0.5f};
    const h4 kTS16 = h4splat(TAUIS_ID);
    auto primal = [&](int rem, bool last) {
        #pragma unroll
        for (int p = 0; p < NPASS; ++p) {
            if (rem >= dth_[p]) {
                int u = tid + p * NT, bF = u * 4;
                int bu = (bF >= UPR * 4) ? bF - PC : bF;  // row-0 junk tolerated
                h4 qvu = *(const h4*)&sQV[bu];
                h4 civ = *(const h4*)&sCI[bF];
                uint32 qhl = *(const unsigned short*)&sQH3[imax(u - 1, 0)];
                uint2 qu = __builtin_bit_cast(uint2, qH[p]);
                h4 qsh = __builtin_bit_cast(h4,
                             make_uint2(abit(qu.x, qhl << 16), abit(qu.y, qu.x)));
                h4 dvg = (qH[p] - qsh) + (qvr[p] - qvu);  // v_pk_sub/add_f16
                h4 s16 = kTS16 * dvg + civ;               // packed f16 fma
                f2 s0 = {(float)s16[0], (float)s16[1]};
                f2 s1 = {(float)s16[2], (float)s16[3]};
                f2 xo0 = xr2[p][0], xo1 = xr2[p][1];
                f2 xn0 = __builtin_elementwise_fma(kID, xo0, s0);
                f2 xn1 = __builtin_elementwise_fma(kID, xo1, s1);
                xr2[p][0] = xn0; xr2[p][1] = xn1;
                f2 xt0 = __builtin_elementwise_fma(k15, xn0, xo0 * km05);
                f2 xt1 = __builtin_elementwise_fma(k15, xn1, xo1 * km05);
                if (!last) {
                    h4 nx = __builtin_bit_cast(h4,
                        make_uint2(pkrtz(xt0[0], xt0[1]),
                                   pkrtz(xt1[0], xt1[1])));
                    xt16[p] = nx;
                    *(h4*)&sXT16[bF] = nx;
                } else {
                    int li = u / UPR, uj = u - li * UPR;
                    int gi = gr0 + li;
                    if (li >= 10 && uj >= 3 && uj <= 18 && gi < M) {
                        *(float4*)&out[(size_t)gi * N + (gc0 + uj * 4)] =
                            make_float4(xt0[0], xt0[1], xt1[0], xt1[1]);
                    }
                }
            }
        }
    };

    primal(9, false);          // t=0 (dual(0) fused into init)
    __syncthreads();
    #pragma unroll 1
    for (int t = 1; t < 9; ++t) {
        int rem = 9 - t;
        dual(rem);
        __syncthreads();
        primal(rem, false);
        __syncthreads();
    }
    dual(0);
    __syncthreads();
    primal(0, true);           // final: global store, no trailing barrier
}

extern "C" void kernel_launch(void* const* d_in, const int* in_sizes, int n_in,
                              void* d_out, int out_size, void* d_ws, size_t ws_size,
                              hipStream_t stream)
{
    const float* img = (const float*)d_in[0];
    const float* w1  = (const float*)d_in[1];
    const float* w2  = (const float*)d_in[2];
    float* out = (float*)d_out;

    dim3 grid(N / TW, GY);   // 32 x 32 = 1024 blocks = 2/CU x 2 rounds
    pd_fused<<<grid, NT, 0, stream>>>(img, out, w1, w2);
}